// Round 1
// baseline (811.439 us; speedup 1.0000x reference)
//
#include <hip/hip_runtime.h>
#include <cstdint>

typedef unsigned long long u64;

#define MAXN 20480
#define MAXNW 320
#define SORT_CHUNK 4096

// ---------------- init ----------------
__global__ void init_out_kernel(int* out, int n) {
    int i = blockIdx.x * blockDim.x + threadIdx.x;
    if (i < n) out[i] = 0;
}

// ---------------- key build ----------------
// key = (descending-orderable score | invalid->0xFFFFFFFF) << 32 | orig_idx
// ascending sort of key == stable descending sort by score (ties: lower idx first)
__global__ void build_keys_kernel(const float* __restrict__ scores,
                                  const float* __restrict__ scoreThrPtr,
                                  u64* __restrict__ keys, int N, int PAD) {
    int i = blockIdx.x * blockDim.x + threadIdx.x;
    if (i >= PAD) return;
    u64 key = ~0ull;
    if (i < N) {
        float s = scores[i];
        float thr = *scoreThrPtr;
        unsigned u = __float_as_uint(s);
        u ^= (u >> 31) ? 0xFFFFFFFFu : 0x80000000u;   // orderable ascending
        unsigned ud = ~u;                              // descending
        if (!(s > thr)) ud = 0xFFFFFFFFu;              // invalid -> end
        key = ((u64)ud << 32) | (unsigned)i;
    }
    keys[i] = key;
}

// ---------------- bitonic sort ----------------
__global__ __launch_bounds__(1024) void bitonic_local_full_kernel(u64* keys) {
    __shared__ u64 lk[SORT_CHUNK];
    int base = blockIdx.x * SORT_CHUNK;
    int t = threadIdx.x;
    for (int u = t; u < SORT_CHUNK; u += 1024) lk[u] = keys[base + u];
    __syncthreads();
    for (int k = 2; k <= SORT_CHUNK; k <<= 1) {
        for (int j = k >> 1; j > 0; j >>= 1) {
            for (int p = t; p < SORT_CHUNK / 2; p += 1024) {
                int i = ((p & ~(j - 1)) << 1) | (p & (j - 1));
                int l = i + j;
                bool up = (((base + i) & k) == 0);
                u64 a = lk[i], b = lk[l];
                if ((a > b) == up) { lk[i] = b; lk[l] = a; }
            }
            __syncthreads();
        }
    }
    for (int u = t; u < SORT_CHUNK; u += 1024) keys[base + u] = lk[u];
}

__global__ void bitonic_global_kernel(u64* keys, int k, int j) {
    int p = blockIdx.x * blockDim.x + threadIdx.x;
    int i = ((p & ~(j - 1)) << 1) | (p & (j - 1));
    int l = i + j;
    bool up = ((i & k) == 0);
    u64 a = keys[i], b = keys[l];
    if ((a > b) == up) { keys[i] = b; keys[l] = a; }
}

__global__ __launch_bounds__(1024) void bitonic_local_tail_kernel(u64* keys, int k) {
    __shared__ u64 lk[SORT_CHUNK];
    int base = blockIdx.x * SORT_CHUNK;
    int t = threadIdx.x;
    for (int u = t; u < SORT_CHUNK; u += 1024) lk[u] = keys[base + u];
    __syncthreads();
    for (int j = SORT_CHUNK / 2; j > 0; j >>= 1) {
        for (int p = t; p < SORT_CHUNK / 2; p += 1024) {
            int i = ((p & ~(j - 1)) << 1) | (p & (j - 1));
            int l = i + j;
            bool up = (((base + i) & k) == 0);
            u64 a = lk[i], b = lk[l];
            if ((a > b) == up) { lk[i] = b; lk[l] = a; }
        }
        __syncthreads();
    }
    for (int u = t; u < SORT_CHUNK; u += 1024) keys[base + u] = lk[u];
}

// ---------------- post-sort gather ----------------
__global__ void make_validw_kernel(const u64* __restrict__ keys,
                                   u64* __restrict__ validw, int N, int NW) {
    int w = blockIdx.x * blockDim.x + threadIdx.x;
    if (w >= NW) return;
    u64 bits = 0;
    for (int b = 0; b < 64; ++b) {
        int r = w * 64 + b;
        if (r < N && (unsigned)(keys[r] >> 32) != 0xFFFFFFFFu) bits |= 1ull << b;
    }
    validw[w] = bits;
}

__global__ void gather_kernel(const u64* __restrict__ keys, const float* __restrict__ boxes,
                              float* __restrict__ sx1, float* __restrict__ sy1,
                              float* __restrict__ sx2, float* __restrict__ sy2,
                              float* __restrict__ areas, int* __restrict__ sorig, int N) {
    int r = blockIdx.x * blockDim.x + threadIdx.x;
    if (r >= N) return;
    int idx = (int)(keys[r] & 0xFFFFFFFFu);
    float4 b = ((const float4*)boxes)[idx];
    sx1[r] = b.x; sy1[r] = b.y; sx2[r] = b.z; sy2[r] = b.w;
    areas[r] = (b.z - b.x) * (b.w - b.y);
    sorig[r] = idx;
}

// ---------------- pairwise IoU mask (upper triangle of 64x64 word tiles) ----------------
__global__ __launch_bounds__(64) void mask_kernel(
        const float* __restrict__ sx1, const float* __restrict__ sy1,
        const float* __restrict__ sx2, const float* __restrict__ sy2,
        const float* __restrict__ areas, const float* __restrict__ iouThrPtr,
        u64* __restrict__ mask, int N, int NW) {
    int wi = blockIdx.x, wj = blockIdx.y;
    if (wj < wi) return;
    __shared__ float jx1[64], jy1[64], jx2[64], jy2[64], ja[64];
    int t = threadIdx.x;
    int j0 = wj << 6;
    int jn = min(64, N - j0);
    if (t < jn) {
        jx1[t] = sx1[j0 + t]; jy1[t] = sy1[j0 + t];
        jx2[t] = sx2[j0 + t]; jy2[t] = sy2[j0 + t];
        ja[t] = areas[j0 + t];
    }
    __syncthreads();
    int i = (wi << 6) + t;
    if (i >= N) return;
    float thr = *iouThrPtr;
    float ix1 = sx1[i], iy1 = sy1[i], ix2 = sx2[i], iy2 = sy2[i], ia = areas[i];
    u64 bits = 0;
    for (int jj = 0; jj < jn; ++jj) {
        int j = j0 + jj;
        if (j > i) {
            float xx1 = fmaxf(ix1, jx1[jj]);
            float yy1 = fmaxf(iy1, jy1[jj]);
            float xx2 = fminf(ix2, jx2[jj]);
            float yy2 = fminf(iy2, jy2[jj]);
            float ww = fmaxf(xx2 - xx1, 0.0f);
            float hh = fmaxf(yy2 - yy1, 0.0f);
            float inter = ww * hh;
            float uni = fmaxf(ia + ja[jj] - inter, 1e-6f);
            if (inter / uni >= thr) bits |= 1ull << jj;
        }
    }
    mask[(size_t)i * NW + wj] = bits;
}

// ---------------- serial greedy scan over the mask ----------------
__global__ __launch_bounds__(MAXNW) void nms_scan_kernel(
        const u64* __restrict__ mask, const u64* __restrict__ validw,
        const int* __restrict__ sorig, int* __restrict__ out,
        int N, int NW, int maxOut) {
    __shared__ u64 S[MAXNW];
    __shared__ int sOrig[MAXN];
    __shared__ int sh_i;
    int t = threadIdx.x;
    for (int w = t; w < NW; w += MAXNW) S[w] = ~validw[w];   // invalid = pre-suppressed
    for (int k = t; k < N; k += MAXNW) sOrig[k] = sorig[k];
    __syncthreads();
    int cnt = 0, w0 = 0;
    while (true) {
        if (t == 0) {
            int found = -1;
            if (cnt < maxOut) {
                while (w0 < NW) {
                    u64 c = ~S[w0];
                    if (c) { found = (w0 << 6) + __builtin_ctzll(c); break; }
                    ++w0;
                }
            }
            sh_i = found;
        }
        __syncthreads();
        int i = sh_i;
        if (i < 0) break;
        int wi = i >> 6;
        if (t == 0) { out[cnt] = sOrig[i]; ++cnt; }
        if (t >= wi && t < NW) {
            u64 r = mask[(size_t)i * NW + t];
            if (t == wi) r |= 1ull << (i & 63);   // mark self handled
            S[t] |= r;
        }
        __syncthreads();
    }
    if (t == 0) out[maxOut] = cnt;
}

// ---------------- fallback: no-mask on-the-fly scan (if ws too small) ----------------
__global__ __launch_bounds__(MAXNW) void nms_scan_fly_kernel(
        const float* __restrict__ sx1, const float* __restrict__ sy1,
        const float* __restrict__ sx2, const float* __restrict__ sy2,
        const float* __restrict__ areas, const u64* __restrict__ validw,
        const int* __restrict__ sorig, const float* __restrict__ iouThrPtr,
        int* __restrict__ out, int N, int NW, int maxOut) {
    __shared__ u64 S[MAXNW];
    __shared__ int sh_i;
    __shared__ float bb[5];
    int t = threadIdx.x;
    for (int w = t; w < NW; w += MAXNW) S[w] = ~validw[w];
    __syncthreads();
    float thr = *iouThrPtr;
    int cnt = 0, w0 = 0;
    while (true) {
        if (t == 0) {
            int found = -1;
            if (cnt < maxOut) {
                while (w0 < NW) {
                    u64 c = ~S[w0];
                    if (c) { found = (w0 << 6) + __builtin_ctzll(c); break; }
                    ++w0;
                }
            }
            sh_i = found;
            if (found >= 0) {
                bb[0] = sx1[found]; bb[1] = sy1[found];
                bb[2] = sx2[found]; bb[3] = sy2[found]; bb[4] = areas[found];
            }
        }
        __syncthreads();
        int i = sh_i;
        if (i < 0) break;
        int wi = i >> 6;
        if (t == 0) { out[cnt] = sorig[i]; ++cnt; }
        for (int w = t; w < NW; w += MAXNW) {
            if (w < wi) continue;
            u64 bits = (w == wi) ? (1ull << (i & 63)) : 0;
            int j0 = w << 6, jn = min(64, N - j0);
            for (int jj = 0; jj < jn; ++jj) {
                int j = j0 + jj;
                if (j > i) {
                    float xx1 = fmaxf(bb[0], sx1[j]);
                    float yy1 = fmaxf(bb[1], sy1[j]);
                    float xx2 = fminf(bb[2], sx2[j]);
                    float yy2 = fminf(bb[3], sy2[j]);
                    float ww = fmaxf(xx2 - xx1, 0.0f);
                    float hh = fmaxf(yy2 - yy1, 0.0f);
                    float inter = ww * hh;
                    float uni = fmaxf(bb[4] + areas[j] - inter, 1e-6f);
                    if (inter / uni >= thr) bits |= 1ull << jj;
                }
            }
            S[w] |= bits;
        }
        __syncthreads();
    }
    if (t == 0) out[maxOut] = cnt;
}

// ---------------- launch ----------------
extern "C" void kernel_launch(void* const* d_in, const int* in_sizes, int n_in,
                              void* d_out, int out_size, void* d_ws, size_t ws_size,
                              hipStream_t stream) {
    const float* boxes      = (const float*)d_in[0];
    const float* scores     = (const float*)d_in[1];
    const float* iouThrPtr  = (const float*)d_in[3];
    const float* scoreThrPtr= (const float*)d_in[4];

    int N  = in_sizes[0] / 4;
    int NW = (N + 63) / 64;
    int NW64 = NW * 64;
    int maxOut = out_size - 1;
    int PAD = SORT_CHUNK; while (PAD < N) PAD <<= 1;

    char* ws = (char*)d_ws;
    size_t off = 0;
    auto take = [&](size_t b) { void* p = ws + off; off = (off + b + 255) & ~(size_t)255; return p; };
    u64*   keys   = (u64*)  take((size_t)PAD * 8);
    float* sx1    = (float*)take((size_t)NW64 * 4);
    float* sy1    = (float*)take((size_t)NW64 * 4);
    float* sx2    = (float*)take((size_t)NW64 * 4);
    float* sy2    = (float*)take((size_t)NW64 * 4);
    float* areas  = (float*)take((size_t)NW64 * 4);
    int*   sorig  = (int*)  take((size_t)NW64 * 4);
    u64*   validw = (u64*)  take((size_t)NW * 8);
    u64*   mask   = (u64*)  take((size_t)N * NW * 8);
    bool useMask = (off <= ws_size);

    init_out_kernel<<<(out_size + 255) / 256, 256, 0, stream>>>((int*)d_out, out_size);
    build_keys_kernel<<<(PAD + 255) / 256, 256, 0, stream>>>(scores, scoreThrPtr, keys, N, PAD);

    bitonic_local_full_kernel<<<PAD / SORT_CHUNK, 1024, 0, stream>>>(keys);
    for (int k = SORT_CHUNK * 2; k <= PAD; k <<= 1) {
        for (int j = k >> 1; j >= SORT_CHUNK; j >>= 1)
            bitonic_global_kernel<<<PAD / 2 / 256, 256, 0, stream>>>(keys, k, j);
        bitonic_local_tail_kernel<<<PAD / SORT_CHUNK, 1024, 0, stream>>>(keys, k);
    }

    make_validw_kernel<<<(NW + 63) / 64, 64, 0, stream>>>(keys, validw, N, NW);
    gather_kernel<<<(N + 255) / 256, 256, 0, stream>>>(keys, boxes, sx1, sy1, sx2, sy2, areas, sorig, N);

    if (useMask) {
        mask_kernel<<<dim3(NW, NW), 64, 0, stream>>>(sx1, sy1, sx2, sy2, areas, iouThrPtr, mask, N, NW);
        nms_scan_kernel<<<1, MAXNW, 0, stream>>>(mask, validw, sorig, (int*)d_out, N, NW, maxOut);
    } else {
        nms_scan_fly_kernel<<<1, MAXNW, 0, stream>>>(sx1, sy1, sx2, sy2, areas, validw, sorig,
                                                     iouThrPtr, (int*)d_out, N, NW, maxOut);
    }
}